// Round 2
// baseline (5654.682 us; speedup 1.0000x reference)
//
#include <hip/hip_runtime.h>
#include <hip/hip_bf16.h>
#include <math.h>

#define NODES 50000
#define EDGES 10000
#define NNZ   800000
#define FIN   128
#define NHID  128
#define FOUT  64

// ---- counts (layer-invariant): cnt_e[e] = #incidences with edge e, cnt_v likewise ----
__global__ __launch_bounds__(256)
void counts_kernel(const int* __restrict__ vertex, const int* __restrict__ edges,
                   float* __restrict__ cnt_v, float* __restrict__ cnt_e) {
    int i = blockIdx.x * blockDim.x + threadIdx.x;
    if (i < NNZ) {
        atomicAdd(&cnt_v[vertex[i]], 1.0f);
        atomicAdd(&cnt_e[edges[i]], 1.0f);
    }
}

// ---- input GEMM: h = relu(x @ W0 + b0); also x0 = h ----
__global__ __launch_bounds__(128)
void gemm_in_kernel(const float* __restrict__ X, const float* __restrict__ W,
                    const float* __restrict__ b, float* __restrict__ h,
                    float* __restrict__ x0) {
    __shared__ float A[8][FIN];
    const int t = threadIdx.x;
    const int row0 = blockIdx.x * 8;
#pragma unroll
    for (int r = 0; r < 8; ++r) A[r][t] = X[(size_t)(row0 + r) * FIN + t];
    __syncthreads();
    float acc[8] = {};
    for (int k = 0; k < FIN; ++k) {
        const float w = W[k * NHID + t];
#pragma unroll
        for (int r = 0; r < 8; ++r) acc[r] += A[r][k] * w;
    }
    const float bias = b[t];
#pragma unroll
    for (int r = 0; r < 8; ++r) {
        float v = acc[r] + bias;
        v = v > 0.f ? v : 0.f;
        h[(size_t)(row0 + r) * NHID + t] = v;
        x0[(size_t)(row0 + r) * NHID + t] = v;
    }
}

// ---- scatter-add: dst[didx[e]] += src[sidx[e]]  (rows of 128 f32) ----
// block = 256 threads = 8 entries x 32 lanes (float4 per lane)
__global__ __launch_bounds__(256)
void scatter_add_kernel(const float* __restrict__ src, const int* __restrict__ sidx,
                        const int* __restrict__ didx, float* __restrict__ dst) {
    const int t = threadIdx.x;
    const int entry = blockIdx.x * 8 + (t >> 5);
    const int lane = t & 31;
    const int s = sidx[entry];
    const int d = didx[entry];
    const float4 v = reinterpret_cast<const float4*>(src + (size_t)s * 128)[lane];
    float* dp = dst + (size_t)d * 128 + lane * 4;
    atomicAdd(dp + 0, v.x);
    atomicAdd(dp + 1, v.y);
    atomicAdd(dp + 2, v.z);
    atomicAdd(dp + 3, v.w);
}

// ---- edge mean: Xe /= max(cnt,1); optionally emit copy to output (last layer) ----
__global__ __launch_bounds__(128)
void edge_mean_kernel(float* __restrict__ Xe, const float* __restrict__ cnt,
                      float* __restrict__ out_xe) {
    const int row = blockIdx.x, t = threadIdx.x;
    float c = cnt[row];
    c = c > 1.f ? c : 1.f;
    const float v = Xe[(size_t)row * NHID + t] / c;
    Xe[(size_t)row * NHID + t] = v;
    if (out_xe) out_xe[(size_t)row * NHID + t] = v;
}

// ---- node post: mean, L2-normalize (detached), residual mix -> Xi (in place) ----
__global__ __launch_bounds__(128)
void node_post_kernel(float* __restrict__ Xv, const float* __restrict__ cnt,
                      const float* __restrict__ x0) {
    __shared__ float part[2];
    const int row = blockIdx.x, t = threadIdx.x;
    float c = cnt[row];
    c = c > 1.f ? c : 1.f;
    const float v = Xv[(size_t)row * NHID + t] / c;
    float s = v * v;
#pragma unroll
    for (int o = 32; o > 0; o >>= 1) s += __shfl_xor(s, o);
    if ((t & 63) == 0) part[t >> 6] = s;
    __syncthreads();
    const float norm = sqrtf(part[0] + part[1]);
    const float scale = norm > 0.f ? 1.0f / fmaxf(norm, 1e-30f) : 0.f;
    const float xi = 0.9f * v * scale + 0.1f * x0[(size_t)row * NHID + t];
    Xv[(size_t)row * NHID + t] = xi;
}

// ---- layer GEMM: x = relu((1-beta)*Xi + beta*(Xi @ W)) ----
__global__ __launch_bounds__(128)
void layer_gemm_kernel(const float* __restrict__ Xi, const float* __restrict__ W,
                       float beta, float* __restrict__ xout) {
    __shared__ float A[8][NHID];
    const int t = threadIdx.x;
    const int row0 = blockIdx.x * 8;
#pragma unroll
    for (int r = 0; r < 8; ++r) A[r][t] = Xi[(size_t)(row0 + r) * NHID + t];
    __syncthreads();
    float acc[8] = {};
    for (int k = 0; k < NHID; ++k) {
        const float w = W[k * NHID + t];
#pragma unroll
        for (int r = 0; r < 8; ++r) acc[r] += A[r][k] * w;
    }
#pragma unroll
    for (int r = 0; r < 8; ++r) {
        float v = (1.f - beta) * A[r][t] + beta * acc[r];
        v = v > 0.f ? v : 0.f;
        xout[(size_t)(row0 + r) * NHID + t] = v;
    }
}

// ---- output GEMM: out = x @ Wout + bout ----
__global__ __launch_bounds__(64)
void out_gemm_kernel(const float* __restrict__ X, const float* __restrict__ W,
                     const float* __restrict__ b, float* __restrict__ out) {
    __shared__ float A[8][NHID];
    const int t = threadIdx.x;
    const int row0 = blockIdx.x * 8;
#pragma unroll
    for (int r = 0; r < 8; ++r) {
        A[r][t] = X[(size_t)(row0 + r) * NHID + t];
        A[r][t + 64] = X[(size_t)(row0 + r) * NHID + t + 64];
    }
    __syncthreads();
    float acc[8] = {};
    for (int k = 0; k < NHID; ++k) {
        const float w = W[k * FOUT + t];
#pragma unroll
        for (int r = 0; r < 8; ++r) acc[r] += A[r][k] * w;
    }
    const float bias = b[t];
#pragma unroll
    for (int r = 0; r < 8; ++r)
        out[(size_t)(row0 + r) * FOUT + t] = acc[r] + bias;
}

extern "C" void kernel_launch(void* const* d_in, const int* in_sizes, int n_in,
                              void* d_out, int out_size, void* d_ws, size_t ws_size,
                              hipStream_t stream) {
    const float* x_in  = (const float*)d_in[0];
    const float* W0    = (const float*)d_in[1];
    const float* b0    = (const float*)d_in[2];
    const float* Ws    = (const float*)d_in[3];
    const float* Wout  = (const float*)d_in[4];
    const float* bout  = (const float*)d_in[5];
    const int* vertex  = (const int*)d_in[6];
    const int* edges   = (const int*)d_in[7];

    float* ws    = (float*)d_ws;
    float* x_cur = ws;                                   // NODES*NHID
    float* x0    = x_cur + (size_t)NODES * NHID;         // NODES*NHID
    float* Xe    = x0    + (size_t)NODES * NHID;         // EDGES*NHID
    float* Xv    = Xe    + (size_t)EDGES * NHID;         // NODES*NHID
    float* cnt_e = Xv    + (size_t)NODES * NHID;         // EDGES
    float* cnt_v = cnt_e + EDGES;                        // NODES
    // total ~82.2 MB of f32 workspace

    float* out    = (float*)d_out;                       // [NODES, FOUT]
    float* out_xe = out + (size_t)NODES * FOUT;          // [EDGES, NHID]

    hipMemsetAsync(cnt_e, 0, (size_t)(EDGES + NODES) * sizeof(float), stream);
    counts_kernel<<<(NNZ + 255) / 256, 256, 0, stream>>>(vertex, edges, cnt_v, cnt_e);

    gemm_in_kernel<<<NODES / 8, 128, 0, stream>>>(x_in, W0, b0, x_cur, x0);

    const float betas[2] = {logf(1.5f), logf(1.25f)};   // log(0.5/(i+1)+1)
    for (int i = 0; i < 2; ++i) {
        hipMemsetAsync(Xe, 0, (size_t)EDGES * NHID * sizeof(float), stream);
        scatter_add_kernel<<<NNZ / 8, 256, 0, stream>>>(x_cur, vertex, edges, Xe);
        edge_mean_kernel<<<EDGES, 128, 0, stream>>>(Xe, cnt_e, (i == 1) ? out_xe : (float*)nullptr);

        hipMemsetAsync(Xv, 0, (size_t)NODES * NHID * sizeof(float), stream);
        scatter_add_kernel<<<NNZ / 8, 256, 0, stream>>>(Xe, edges, vertex, Xv);
        node_post_kernel<<<NODES, 128, 0, stream>>>(Xv, cnt_v, x0);

        layer_gemm_kernel<<<NODES / 8, 128, 0, stream>>>(Xv, Ws + (size_t)i * NHID * NHID,
                                                         betas[i], x_cur);
    }

    out_gemm_kernel<<<NODES / 8, 64, 0, stream>>>(x_cur, Wout, bout, out);
}

// Round 3
// 584.436 us; speedup vs baseline: 9.6755x; 9.6755x over previous
//
#include <hip/hip_runtime.h>
#include <hip/hip_bf16.h>
#include <math.h>

#define NODES 50000
#define EDGES 10000
#define NNZ   800000
#define FIN   128
#define NHID  128
#define FOUT  64

// ---- histogram of destination indices (int atomics, cheap) ----
__global__ __launch_bounds__(256)
void hist_kernel(const int* __restrict__ vertex, const int* __restrict__ edges,
                 int* __restrict__ cnt_v, int* __restrict__ cnt_e) {
    int i = blockIdx.x * blockDim.x + threadIdx.x;
    if (i < NNZ) {
        atomicAdd(&cnt_e[edges[i]], 1);
        atomicAdd(&cnt_v[vertex[i]], 1);
    }
}

// ---- exclusive scan (single block, wave-scan + LDS); gridDim.x==2 picks array ----
__global__ __launch_bounds__(1024)
void scan_kernel(const int* __restrict__ cnt_e, int* __restrict__ rp_e, int* __restrict__ cur_e,
                 const int* __restrict__ cnt_v, int* __restrict__ rp_v, int* __restrict__ cur_v) {
    const int* cnt = (blockIdx.x == 0) ? cnt_e : cnt_v;
    int* rp  = (blockIdx.x == 0) ? rp_e  : rp_v;
    int* cur = (blockIdx.x == 0) ? cur_e : cur_v;
    const int n = (blockIdx.x == 0) ? EDGES : NODES;

    __shared__ int wsum[16];
    __shared__ int carry_sh;
    const int t = threadIdx.x, lane = t & 63, w = t >> 6;
    if (t == 0) carry_sh = 0;
    __syncthreads();
    for (int base = 0; base < n; base += 1024) {
        const int v = (base + t < n) ? cnt[base + t] : 0;
        int x = v;
#pragma unroll
        for (int o = 1; o < 64; o <<= 1) {
            int y = __shfl_up(x, o);
            if (lane >= o) x += y;
        }
        if (lane == 63) wsum[w] = x;
        __syncthreads();
        if (t < 16) {
            int s = wsum[t];
#pragma unroll
            for (int o = 1; o < 16; o <<= 1) {
                int y = __shfl_up(s, o);
                if (t >= o) s += y;
            }
            wsum[t] = s;
        }
        __syncthreads();
        const int incl = x + (w ? wsum[w - 1] : 0);
        const int carry = carry_sh;
        if (base + t < n) {
            const int p = carry + incl - v;
            rp[base + t] = p;
            cur[base + t] = p;
        }
        __syncthreads();
        if (t == 1023) carry_sh = carry + wsum[15];
        __syncthreads();
    }
    if (t == 0) rp[n] = carry_sh;
}

// ---- CSR fill via cursors ----
__global__ __launch_bounds__(256)
void fill_kernel(const int* __restrict__ vertex, const int* __restrict__ edges,
                 int* __restrict__ cur_e, int* __restrict__ cur_v,
                 int* __restrict__ col_e, int* __restrict__ col_v) {
    int i = blockIdx.x * blockDim.x + threadIdx.x;
    if (i < NNZ) {
        const int e = edges[i], v = vertex[i];
        col_e[atomicAdd(&cur_e[e], 1)] = v;   // edge-CSR stores source node
        col_v[atomicAdd(&cur_v[v], 1)] = e;   // node-CSR stores source edge
    }
}

// ---- input GEMM: h = relu(x @ W0 + b0); also x0 = h ----
__global__ __launch_bounds__(128)
void gemm_in_kernel(const float* __restrict__ X, const float* __restrict__ W,
                    const float* __restrict__ b, float* __restrict__ h,
                    float* __restrict__ x0) {
    __shared__ float A[8][FIN];
    const int t = threadIdx.x;
    const int row0 = blockIdx.x * 8;
#pragma unroll
    for (int r = 0; r < 8; ++r) A[r][t] = X[(size_t)(row0 + r) * FIN + t];
    __syncthreads();
    float acc[8] = {};
    for (int k = 0; k < FIN; ++k) {
        const float w = W[k * NHID + t];
#pragma unroll
        for (int r = 0; r < 8; ++r) acc[r] += A[r][k] * w;
    }
    const float bias = b[t];
#pragma unroll
    for (int r = 0; r < 8; ++r) {
        float v = acc[r] + bias;
        v = v > 0.f ? v : 0.f;
        h[(size_t)(row0 + r) * NHID + t] = v;
        x0[(size_t)(row0 + r) * NHID + t] = v;
    }
}

// ---- edge gather + mean: Xe[e] = mean_{j in row e} x[col[j]]; optional copy out ----
__global__ __launch_bounds__(128)
void edge_gather_kernel(const float* __restrict__ x, const int* __restrict__ rp,
                        const int* __restrict__ ci, float* __restrict__ Xe,
                        float* __restrict__ out_xe) {
    __shared__ int idx[128];
    const int e = blockIdx.x, t = threadIdx.x;
    const int beg = rp[e], end = rp[e + 1];
    float acc = 0.f;
    for (int base = beg; base < end; base += 128) {
        const int m = min(128, end - base);
        if (t < m) idx[t] = ci[base + t];
        __syncthreads();
#pragma unroll 4
        for (int j = 0; j < m; ++j)
            acc += x[(size_t)idx[j] * NHID + t];
        __syncthreads();
    }
    const float v = acc / (float)max(end - beg, 1);
    Xe[(size_t)e * NHID + t] = v;
    if (out_xe) out_xe[(size_t)e * NHID + t] = v;
}

// ---- node gather + mean + L2-normalize + residual mix -> Xi ----
__global__ __launch_bounds__(128)
void node_gather_post_kernel(const float* __restrict__ Xe, const int* __restrict__ rp,
                             const int* __restrict__ ci, const float* __restrict__ x0,
                             float* __restrict__ xout) {
    __shared__ int idx[128];
    __shared__ float part[2];
    const int v = blockIdx.x, t = threadIdx.x;
    const int beg = rp[v], end = rp[v + 1];
    float acc = 0.f;
    for (int base = beg; base < end; base += 128) {
        const int m = min(128, end - base);
        if (t < m) idx[t] = ci[base + t];
        __syncthreads();
#pragma unroll 4
        for (int j = 0; j < m; ++j)
            acc += Xe[(size_t)idx[j] * NHID + t];
        __syncthreads();
    }
    const float mean = acc / (float)max(end - beg, 1);
    float s = mean * mean;
#pragma unroll
    for (int o = 32; o > 0; o >>= 1) s += __shfl_xor(s, o);
    if ((t & 63) == 0) part[t >> 6] = s;
    __syncthreads();
    const float norm = sqrtf(part[0] + part[1]);
    const float scale = norm > 0.f ? 1.f / fmaxf(norm, 1e-30f) : 0.f;
    xout[(size_t)v * NHID + t] = 0.9f * mean * scale + 0.1f * x0[(size_t)v * NHID + t];
}

// ---- layer GEMM (in place): x = relu((1-beta)*x + beta*(x @ W)) ----
__global__ __launch_bounds__(128)
void layer_gemm_kernel(float* __restrict__ X, const float* __restrict__ W, float beta) {
    __shared__ float A[8][NHID];
    const int t = threadIdx.x;
    const int row0 = blockIdx.x * 8;
#pragma unroll
    for (int r = 0; r < 8; ++r) A[r][t] = X[(size_t)(row0 + r) * NHID + t];
    __syncthreads();
    float acc[8] = {};
    for (int k = 0; k < NHID; ++k) {
        const float w = W[k * NHID + t];
#pragma unroll
        for (int r = 0; r < 8; ++r) acc[r] += A[r][k] * w;
    }
#pragma unroll
    for (int r = 0; r < 8; ++r) {
        float v = (1.f - beta) * A[r][t] + beta * acc[r];
        v = v > 0.f ? v : 0.f;
        X[(size_t)(row0 + r) * NHID + t] = v;
    }
}

// ---- output GEMM: out = x @ Wout + bout ----
__global__ __launch_bounds__(64)
void out_gemm_kernel(const float* __restrict__ X, const float* __restrict__ W,
                     const float* __restrict__ b, float* __restrict__ out) {
    __shared__ float A[8][NHID];
    const int t = threadIdx.x;
    const int row0 = blockIdx.x * 8;
#pragma unroll
    for (int r = 0; r < 8; ++r) {
        A[r][t] = X[(size_t)(row0 + r) * NHID + t];
        A[r][t + 64] = X[(size_t)(row0 + r) * NHID + t + 64];
    }
    __syncthreads();
    float acc[8] = {};
    for (int k = 0; k < NHID; ++k) {
        const float w = W[k * FOUT + t];
#pragma unroll
        for (int r = 0; r < 8; ++r) acc[r] += A[r][k] * w;
    }
    const float bias = b[t];
#pragma unroll
    for (int r = 0; r < 8; ++r)
        out[(size_t)(row0 + r) * FOUT + t] = acc[r] + bias;
}

extern "C" void kernel_launch(void* const* d_in, const int* in_sizes, int n_in,
                              void* d_out, int out_size, void* d_ws, size_t ws_size,
                              hipStream_t stream) {
    const float* x_in  = (const float*)d_in[0];
    const float* W0    = (const float*)d_in[1];
    const float* b0    = (const float*)d_in[2];
    const float* Ws    = (const float*)d_in[3];
    const float* Wout  = (const float*)d_in[4];
    const float* bout  = (const float*)d_in[5];
    const int* vertex  = (const int*)d_in[6];
    const int* edges   = (const int*)d_in[7];

    float* fw   = (float*)d_ws;
    float* x    = fw;                                  // NODES*NHID   (25.6 MB)
    float* x0   = x  + (size_t)NODES * NHID;           // NODES*NHID   (25.6 MB)
    float* Xe   = x0 + (size_t)NODES * NHID;           // EDGES*NHID   (5.1 MB)
    int*  iw    = (int*)(Xe + (size_t)EDGES * NHID);
    int* cnt_e  = iw;                                  // EDGES
    int* cnt_v  = cnt_e + EDGES;                       // NODES
    int* rp_e   = cnt_v + NODES;                       // EDGES+1
    int* cur_e  = rp_e + EDGES + 1;                    // EDGES
    int* rp_v   = cur_e + EDGES;                       // NODES+1
    int* cur_v  = rp_v + NODES + 1;                    // NODES
    int* col_e  = cur_v + NODES;                       // NNZ
    int* col_v  = col_e + NNZ;                         // NNZ
    // total ≈ 63.3 MB

    float* out    = (float*)d_out;                     // [NODES, FOUT]
    float* out_xe = out + (size_t)NODES * FOUT;        // [EDGES, NHID]

    // ---- build CSR (edge-major and node-major) ----
    hipMemsetAsync(cnt_e, 0, (size_t)(EDGES + NODES) * sizeof(int), stream);
    hist_kernel<<<(NNZ + 255) / 256, 256, 0, stream>>>(vertex, edges, cnt_v, cnt_e);
    scan_kernel<<<2, 1024, 0, stream>>>(cnt_e, rp_e, cur_e, cnt_v, rp_v, cur_v);
    fill_kernel<<<(NNZ + 255) / 256, 256, 0, stream>>>(vertex, edges, cur_e, cur_v, col_e, col_v);

    // ---- input layer ----
    gemm_in_kernel<<<NODES / 8, 128, 0, stream>>>(x_in, W0, b0, x, x0);

    const float betas[2] = {logf(1.5f), logf(1.25f)};  // log(0.5/(i+1)+1)
    for (int i = 0; i < 2; ++i) {
        edge_gather_kernel<<<EDGES, 128, 0, stream>>>(x, rp_e, col_e, Xe,
                                                      (i == 1) ? out_xe : (float*)nullptr);
        node_gather_post_kernel<<<NODES, 128, 0, stream>>>(Xe, rp_v, col_v, x0, x);
        layer_gemm_kernel<<<NODES / 8, 128, 0, stream>>>(x, Ws + (size_t)i * NHID * NHID,
                                                         betas[i]);
    }

    out_gemm_kernel<<<NODES / 8, 64, 0, stream>>>(x, Wout, bout, out);
}

// Round 4
// 507.935 us; speedup vs baseline: 11.1327x; 1.1506x over previous
//
#include <hip/hip_runtime.h>
#include <hip/hip_bf16.h>
#include <math.h>

#define NODES 50000
#define EDGES 10000
#define NNZ   800000
#define FIN   128
#define NHID  128
#define FOUT  64

typedef __attribute__((ext_vector_type(8))) short bf16x8;
typedef __attribute__((ext_vector_type(4))) float f32x4;
typedef unsigned short ushort_t;

__device__ __forceinline__ ushort_t f2b(float f) {
    __hip_bfloat16 h = __float2bfloat16(f);
    return *reinterpret_cast<ushort_t*>(&h);
}
__device__ __forceinline__ float b2f(ushort_t u) {
    __hip_bfloat16 h;
    *reinterpret_cast<ushort_t*>(&h) = u;
    return __bfloat162float(h);
}

// ---- weights: transpose + convert to bf16 (Wt[c][k] = W[k][c]) ----
__global__ __launch_bounds__(256)
void wconv_kernel(const float* __restrict__ W0, const float* __restrict__ Ws,
                  const float* __restrict__ Wout,
                  ushort_t* __restrict__ Wt0, ushort_t* __restrict__ WsT,
                  ushort_t* __restrict__ WoutT) {
    const int i = blockIdx.x * 256 + threadIdx.x;
    if (i < 128 * 128) { int c = i >> 7, k = i & 127; Wt0[c * 128 + k] = f2b(W0[k * 128 + c]); }
    if (i < 2 * 128 * 128) {
        int l = i >> 14, r = i & 16383, c = r >> 7, k = r & 127;
        WsT[l * 16384 + c * 128 + k] = f2b(Ws[l * 16384 + k * 128 + c]);
    }
    if (i < 64 * 128) { int c = i >> 7, k = i & 127; WoutT[c * 128 + k] = f2b(Wout[k * 64 + c]); }
}

// ---- histogram of destination indices ----
__global__ __launch_bounds__(256)
void hist_kernel(const int* __restrict__ vertex, const int* __restrict__ edges,
                 int* __restrict__ cnt_v, int* __restrict__ cnt_e) {
    int i = blockIdx.x * blockDim.x + threadIdx.x;
    if (i < NNZ) {
        atomicAdd(&cnt_e[edges[i]], 1);
        atomicAdd(&cnt_v[vertex[i]], 1);
    }
}

// ---- exclusive scan (one block per array) ----
__global__ __launch_bounds__(1024)
void scan_kernel(const int* __restrict__ cnt_e, int* __restrict__ rp_e, int* __restrict__ cur_e,
                 const int* __restrict__ cnt_v, int* __restrict__ rp_v, int* __restrict__ cur_v) {
    const int* cnt = (blockIdx.x == 0) ? cnt_e : cnt_v;
    int* rp  = (blockIdx.x == 0) ? rp_e  : rp_v;
    int* cur = (blockIdx.x == 0) ? cur_e : cur_v;
    const int n = (blockIdx.x == 0) ? EDGES : NODES;

    __shared__ int wsum[16];
    __shared__ int carry_sh;
    const int t = threadIdx.x, lane = t & 63, w = t >> 6;
    if (t == 0) carry_sh = 0;
    __syncthreads();
    for (int base = 0; base < n; base += 1024) {
        const int v = (base + t < n) ? cnt[base + t] : 0;
        int x = v;
#pragma unroll
        for (int o = 1; o < 64; o <<= 1) {
            int y = __shfl_up(x, o);
            if (lane >= o) x += y;
        }
        if (lane == 63) wsum[w] = x;
        __syncthreads();
        if (t < 16) {
            int s = wsum[t];
#pragma unroll
            for (int o = 1; o < 16; o <<= 1) {
                int y = __shfl_up(s, o);
                if (t >= o) s += y;
            }
            wsum[t] = s;
        }
        __syncthreads();
        const int incl = x + (w ? wsum[w - 1] : 0);
        const int carry = carry_sh;
        if (base + t < n) {
            const int p = carry + incl - v;
            rp[base + t] = p;
            cur[base + t] = p;
        }
        __syncthreads();
        if (t == 1023) carry_sh = carry + wsum[15];
        __syncthreads();
    }
    if (t == 0) rp[n] = carry_sh;
}

// ---- CSR fill via cursors (nontemporal scattered stores) ----
__global__ __launch_bounds__(256)
void fill_kernel(const int* __restrict__ vertex, const int* __restrict__ edges,
                 int* __restrict__ cur_e, int* __restrict__ cur_v,
                 int* __restrict__ col_e, int* __restrict__ col_v) {
    int i = blockIdx.x * blockDim.x + threadIdx.x;
    if (i < NNZ) {
        const int e = edges[i], v = vertex[i];
        const int pe = atomicAdd(&cur_e[e], 1);
        __builtin_nontemporal_store(v, &col_e[pe]);
        const int pv = atomicAdd(&cur_v[v], 1);
        __builtin_nontemporal_store(e, &col_v[pv]);
    }
}

// ---- input GEMM (MFMA): x = x0 = relu(Xin @ W0 + b0), bf16 out ----
__global__ __launch_bounds__(256)
void gemm_in_kernel(const float* __restrict__ X, const ushort_t* __restrict__ Wt,
                    const float* __restrict__ bias,
                    ushort_t* __restrict__ x, ushort_t* __restrict__ x0) {
    const int lane = threadIdx.x & 63, wave = threadIdx.x >> 6;
    const int row0 = blockIdx.x * 64 + wave * 16;
    if (row0 >= NODES) return;
    const int r = lane & 15, kb = lane >> 4;
    const int row = row0 + r;
    bf16x8 a[4];
#pragma unroll
    for (int k0 = 0; k0 < 4; ++k0) {
        const float* p = X + (size_t)row * FIN + k0 * 32 + kb * 8;
        const float4 lo = *(const float4*)p;
        const float4 hi = *(const float4*)(p + 4);
        bf16x8 t;
        t[0] = f2b(lo.x); t[1] = f2b(lo.y); t[2] = f2b(lo.z); t[3] = f2b(lo.w);
        t[4] = f2b(hi.x); t[5] = f2b(hi.y); t[6] = f2b(hi.z); t[7] = f2b(hi.w);
        a[k0] = t;
    }
    f32x4 acc[8];
#pragma unroll
    for (int c0 = 0; c0 < 8; ++c0) {
        const float bv = bias[c0 * 16 + r];
        acc[c0] = (f32x4){bv, bv, bv, bv};
    }
#pragma unroll
    for (int k0 = 0; k0 < 4; ++k0)
#pragma unroll
        for (int c0 = 0; c0 < 8; ++c0) {
            const bf16x8 b = *(const bf16x8*)(Wt + (size_t)(c0 * 16 + r) * FIN + k0 * 32 + kb * 8);
            acc[c0] = __builtin_amdgcn_mfma_f32_16x16x32_bf16(a[k0], b, acc[c0], 0, 0, 0);
        }
#pragma unroll
    for (int c0 = 0; c0 < 8; ++c0) {
        const int col = c0 * 16 + r;
#pragma unroll
        for (int v = 0; v < 4; ++v) {
            const int orow = row0 + kb * 4 + v;
            float val = acc[c0][v];
            val = val > 0.f ? val : 0.f;
            const ushort_t ub = f2b(val);
            x [(size_t)orow * NHID + col] = ub;
            x0[(size_t)orow * NHID + col] = ub;
        }
    }
}

// ---- edge gather + mean: Xe[e] = mean x[col[j]] (bf16 in, f32 out) ----
__global__ __launch_bounds__(128)
void edge_gather_kernel(const ushort_t* __restrict__ x, const int* __restrict__ rp,
                        const int* __restrict__ ci, float* __restrict__ Xe,
                        float* __restrict__ out_xe) {
    __shared__ int idx[128];
    const int e = blockIdx.x, t = threadIdx.x;
    const int beg = rp[e], end = rp[e + 1];
    float acc = 0.f;
    for (int base = beg; base < end; base += 128) {
        const int m = min(128, end - base);
        if (t < m) idx[t] = ci[base + t];
        __syncthreads();
#pragma unroll 4
        for (int j = 0; j < m; ++j)
            acc += b2f(x[(size_t)idx[j] * NHID + t]);
        __syncthreads();
    }
    const float v = acc / (float)max(end - beg, 1);
    Xe[(size_t)e * NHID + t] = v;
    if (out_xe) out_xe[(size_t)e * NHID + t] = v;
}

// ---- node gather + mean + L2-normalize + residual -> x (bf16) ----
__global__ __launch_bounds__(128)
void node_gather_post_kernel(const float* __restrict__ Xe, const int* __restrict__ rp,
                             const int* __restrict__ ci, const ushort_t* __restrict__ x0,
                             ushort_t* __restrict__ x) {
    __shared__ int idx[128];
    __shared__ float part[2];
    const int v = blockIdx.x, t = threadIdx.x;
    const int beg = rp[v], end = rp[v + 1];
    float acc = 0.f;
    for (int base = beg; base < end; base += 128) {
        const int m = min(128, end - base);
        if (t < m) idx[t] = ci[base + t];
        __syncthreads();
#pragma unroll 4
        for (int j = 0; j < m; ++j)
            acc += Xe[(size_t)idx[j] * NHID + t];
        __syncthreads();
    }
    const float mean = acc / (float)max(end - beg, 1);
    float s = mean * mean;
#pragma unroll
    for (int o = 32; o > 0; o >>= 1) s += __shfl_xor(s, o);
    if ((t & 63) == 0) part[t >> 6] = s;
    __syncthreads();
    const float norm = sqrtf(part[0] + part[1]);
    const float scale = norm > 0.f ? 1.f / fmaxf(norm, 1e-30f) : 0.f;
    const size_t off = (size_t)v * NHID + t;
    x[off] = f2b(0.9f * mean * scale + 0.1f * b2f(x0[off]));
}

// ---- layer GEMM (MFMA, in place): x = relu((1-beta)*x + beta*(x @ W)) ----
__global__ __launch_bounds__(256)
void layer_gemm_kernel(ushort_t* __restrict__ x, const ushort_t* __restrict__ Wt, float beta) {
    const int lane = threadIdx.x & 63, wave = threadIdx.x >> 6;
    const int row0 = blockIdx.x * 64 + wave * 16;
    if (row0 >= NODES) return;
    const int r = lane & 15, kb = lane >> 4;
    const int row = row0 + r;
    bf16x8 a[4];
#pragma unroll
    for (int k0 = 0; k0 < 4; ++k0)
        a[k0] = *(const bf16x8*)(x + (size_t)row * NHID + k0 * 32 + kb * 8);
    f32x4 acc[8] = {};
#pragma unroll
    for (int k0 = 0; k0 < 4; ++k0)
#pragma unroll
        for (int c0 = 0; c0 < 8; ++c0) {
            const bf16x8 b = *(const bf16x8*)(Wt + (size_t)(c0 * 16 + r) * NHID + k0 * 32 + kb * 8);
            acc[c0] = __builtin_amdgcn_mfma_f32_16x16x32_bf16(a[k0], b, acc[c0], 0, 0, 0);
        }
#pragma unroll
    for (int c0 = 0; c0 < 8; ++c0) {
        const int col = c0 * 16 + r;
#pragma unroll
        for (int v = 0; v < 4; ++v) {
            const int orow = row0 + kb * 4 + v;
            const size_t off = (size_t)orow * NHID + col;
            const float xi = b2f(x[off]);
            float val = (1.f - beta) * xi + beta * acc[c0][v];
            val = val > 0.f ? val : 0.f;
            x[off] = f2b(val);
        }
    }
}

// ---- output GEMM (MFMA): out = x @ Wout + bout (f32 out) ----
__global__ __launch_bounds__(256)
void out_gemm_kernel(const ushort_t* __restrict__ x, const ushort_t* __restrict__ Wt,
                     const float* __restrict__ bias, float* __restrict__ out) {
    const int lane = threadIdx.x & 63, wave = threadIdx.x >> 6;
    const int row0 = blockIdx.x * 64 + wave * 16;
    if (row0 >= NODES) return;
    const int r = lane & 15, kb = lane >> 4;
    const int row = row0 + r;
    bf16x8 a[4];
#pragma unroll
    for (int k0 = 0; k0 < 4; ++k0)
        a[k0] = *(const bf16x8*)(x + (size_t)row * NHID + k0 * 32 + kb * 8);
    f32x4 acc[4];
#pragma unroll
    for (int c0 = 0; c0 < 4; ++c0) {
        const float bv = bias[c0 * 16 + r];
        acc[c0] = (f32x4){bv, bv, bv, bv};
    }
#pragma unroll
    for (int k0 = 0; k0 < 4; ++k0)
#pragma unroll
        for (int c0 = 0; c0 < 4; ++c0) {
            const bf16x8 b = *(const bf16x8*)(Wt + (size_t)(c0 * 16 + r) * NHID + k0 * 32 + kb * 8);
            acc[c0] = __builtin_amdgcn_mfma_f32_16x16x32_bf16(a[k0], b, acc[c0], 0, 0, 0);
        }
#pragma unroll
    for (int c0 = 0; c0 < 4; ++c0) {
        const int col = c0 * 16 + r;
#pragma unroll
        for (int v = 0; v < 4; ++v) {
            const int orow = row0 + kb * 4 + v;
            out[(size_t)orow * FOUT + col] = acc[c0][v];
        }
    }
}

extern "C" void kernel_launch(void* const* d_in, const int* in_sizes, int n_in,
                              void* d_out, int out_size, void* d_ws, size_t ws_size,
                              hipStream_t stream) {
    const float* x_in  = (const float*)d_in[0];
    const float* W0    = (const float*)d_in[1];
    const float* b0    = (const float*)d_in[2];
    const float* Ws    = (const float*)d_in[3];
    const float* Wout  = (const float*)d_in[4];
    const float* bout  = (const float*)d_in[5];
    const int* vertex  = (const int*)d_in[6];
    const int* edges   = (const int*)d_in[7];

    float* Xe      = (float*)d_ws;                          // EDGES*NHID f32
    ushort_t* x    = (ushort_t*)(Xe + (size_t)EDGES * NHID);// NODES*NHID bf16
    ushort_t* x0   = x  + (size_t)NODES * NHID;             // NODES*NHID bf16
    ushort_t* Wt0  = x0 + (size_t)NODES * NHID;             // 128*128
    ushort_t* WsT  = Wt0 + 128 * 128;                       // 2*128*128
    ushort_t* WoutT= WsT + 2 * 128 * 128;                   // 64*128
    int* cnt_e = (int*)(WoutT + 64 * 128);                  // EDGES
    int* cnt_v = cnt_e + EDGES;                             // NODES
    int* rp_e  = cnt_v + NODES;                             // EDGES+1
    int* cur_e = rp_e + EDGES + 1;                          // EDGES
    int* rp_v  = cur_e + EDGES;                             // NODES+1
    int* cur_v = rp_v + NODES + 1;                          // NODES
    int* col_e = cur_v + NODES;                             // NNZ
    int* col_v = col_e + NNZ;                               // NNZ

    float* out    = (float*)d_out;                          // [NODES, FOUT]
    float* out_xe = out + (size_t)NODES * FOUT;             // [EDGES, NHID]

    // ---- CSR build + weight conversion ----
    hipMemsetAsync(cnt_e, 0, (size_t)(EDGES + NODES) * sizeof(int), stream);
    wconv_kernel<<<128, 256, 0, stream>>>(W0, Ws, Wout, Wt0, WsT, WoutT);
    hist_kernel<<<(NNZ + 255) / 256, 256, 0, stream>>>(vertex, edges, cnt_v, cnt_e);
    scan_kernel<<<2, 1024, 0, stream>>>(cnt_e, rp_e, cur_e, cnt_v, rp_v, cur_v);
    fill_kernel<<<(NNZ + 255) / 256, 256, 0, stream>>>(vertex, edges, cur_e, cur_v, col_e, col_v);

    const int gemm_grid = (NODES + 63) / 64;
    gemm_in_kernel<<<gemm_grid, 256, 0, stream>>>(x_in, Wt0, b0, x, x0);

    const float betas[2] = {logf(1.5f), logf(1.25f)};  // log(0.5/(i+1)+1)
    for (int i = 0; i < 2; ++i) {
        edge_gather_kernel<<<EDGES, 128, 0, stream>>>(x, rp_e, col_e, Xe,
                                                      (i == 1) ? out_xe : (float*)nullptr);
        node_gather_post_kernel<<<NODES, 128, 0, stream>>>(Xe, rp_v, col_v, x0, x);
        layer_gemm_kernel<<<gemm_grid, 256, 0, stream>>>(x, WsT + (size_t)i * NHID * NHID,
                                                         betas[i]);
    }

    out_gemm_kernel<<<gemm_grid, 256, 0, stream>>>(x, WoutT, bout, out);
}

// Round 5
// 498.978 us; speedup vs baseline: 11.3325x; 1.0180x over previous
//
#include <hip/hip_runtime.h>
#include <hip/hip_bf16.h>
#include <math.h>

#define NODES 50000
#define EDGES 10000
#define NNZ   800000
#define FIN   128
#define NHID  128
#define FOUT  64

typedef __attribute__((ext_vector_type(8))) short bf16x8;
typedef __attribute__((ext_vector_type(4))) float f32x4;
typedef unsigned short ushort_t;

__device__ __forceinline__ ushort_t f2b(float f) {
    __hip_bfloat16 h = __float2bfloat16(f);
    return *reinterpret_cast<ushort_t*>(&h);
}
__device__ __forceinline__ float b2f(ushort_t u) {
    __hip_bfloat16 h;
    *reinterpret_cast<ushort_t*>(&h) = u;
    return __bfloat162float(h);
}
__device__ __forceinline__ float u2f(unsigned u) {
    union { unsigned u; float f; } c; c.u = u; return c.f;
}

// ---- weights: transpose + convert to bf16 (Wt[c][k] = W[k][c]) ----
__global__ __launch_bounds__(256)
void wconv_kernel(const float* __restrict__ W0, const float* __restrict__ Ws,
                  const float* __restrict__ Wout,
                  ushort_t* __restrict__ Wt0, ushort_t* __restrict__ WsT,
                  ushort_t* __restrict__ WoutT) {
    const int i = blockIdx.x * 256 + threadIdx.x;
    if (i < 128 * 128) { int c = i >> 7, k = i & 127; Wt0[c * 128 + k] = f2b(W0[k * 128 + c]); }
    if (i < 2 * 128 * 128) {
        int l = i >> 14, r = i & 16383, c = r >> 7, k = r & 127;
        WsT[l * 16384 + c * 128 + k] = f2b(Ws[l * 16384 + k * 128 + c]);
    }
    if (i < 64 * 128) { int c = i >> 7, k = i & 127; WoutT[c * 128 + k] = f2b(Wout[k * 64 + c]); }
}

// ---- histogram + per-entry rank (atomic return value), ranks stored coalesced ----
__global__ __launch_bounds__(256)
void hist_kernel(const int* __restrict__ vertex, const int* __restrict__ edges,
                 int* __restrict__ cnt_v, int* __restrict__ cnt_e,
                 int* __restrict__ rank_v, int* __restrict__ rank_e) {
    int i = blockIdx.x * blockDim.x + threadIdx.x;
    if (i < NNZ) {
        rank_e[i] = atomicAdd(&cnt_e[edges[i]], 1);
        rank_v[i] = atomicAdd(&cnt_v[vertex[i]], 1);
    }
}

// ---- exclusive scan (one block per array) ----
__global__ __launch_bounds__(1024)
void scan_kernel(const int* __restrict__ cnt_e, int* __restrict__ rp_e,
                 const int* __restrict__ cnt_v, int* __restrict__ rp_v) {
    const int* cnt = (blockIdx.x == 0) ? cnt_e : cnt_v;
    int* rp  = (blockIdx.x == 0) ? rp_e  : rp_v;
    const int n = (blockIdx.x == 0) ? EDGES : NODES;

    __shared__ int wsum[16];
    __shared__ int carry_sh;
    const int t = threadIdx.x, lane = t & 63, w = t >> 6;
    if (t == 0) carry_sh = 0;
    __syncthreads();
    for (int base = 0; base < n; base += 1024) {
        const int v = (base + t < n) ? cnt[base + t] : 0;
        int x = v;
#pragma unroll
        for (int o = 1; o < 64; o <<= 1) {
            int y = __shfl_up(x, o);
            if (lane >= o) x += y;
        }
        if (lane == 63) wsum[w] = x;
        __syncthreads();
        if (t < 16) {
            int s = wsum[t];
#pragma unroll
            for (int o = 1; o < 16; o <<= 1) {
                int y = __shfl_up(s, o);
                if (t >= o) s += y;
            }
            wsum[t] = s;
        }
        __syncthreads();
        const int incl = x + (w ? wsum[w - 1] : 0);
        const int carry = carry_sh;
        if (base + t < n) rp[base + t] = carry + incl - v;
        __syncthreads();
        if (t == 1023) carry_sh = carry + wsum[15];
        __syncthreads();
    }
    if (t == 0) rp[n] = carry_sh;
}

// ---- CSR fill: position = rp[key] + rank  (independent scattered stores, no RMW) ----
__global__ __launch_bounds__(256)
void fill_kernel(const int* __restrict__ vertex, const int* __restrict__ edges,
                 const int* __restrict__ rank_e, const int* __restrict__ rank_v,
                 const int* __restrict__ rp_e, const int* __restrict__ rp_v,
                 int* __restrict__ col_e, int* __restrict__ col_v) {
    int i = blockIdx.x * blockDim.x + threadIdx.x;
    if (i < NNZ) {
        const int e = edges[i], v = vertex[i];
        __builtin_nontemporal_store(v, &col_e[rp_e[e] + rank_e[i]]);
        __builtin_nontemporal_store(e, &col_v[rp_v[v] + rank_v[i]]);
    }
}

// ---- input GEMM (MFMA): x = x0 = relu(Xin @ W0 + b0), bf16 out ----
__global__ __launch_bounds__(256)
void gemm_in_kernel(const float* __restrict__ X, const ushort_t* __restrict__ Wt,
                    const float* __restrict__ bias,
                    ushort_t* __restrict__ x, ushort_t* __restrict__ x0) {
    const int lane = threadIdx.x & 63, wave = threadIdx.x >> 6;
    const int row0 = blockIdx.x * 64 + wave * 16;
    if (row0 >= NODES) return;
    const int r = lane & 15, kb = lane >> 4;
    const int row = row0 + r;
    bf16x8 a[4];
#pragma unroll
    for (int k0 = 0; k0 < 4; ++k0) {
        const float* p = X + (size_t)row * FIN + k0 * 32 + kb * 8;
        const float4 lo = *(const float4*)p;
        const float4 hi = *(const float4*)(p + 4);
        bf16x8 t;
        t[0] = f2b(lo.x); t[1] = f2b(lo.y); t[2] = f2b(lo.z); t[3] = f2b(lo.w);
        t[4] = f2b(hi.x); t[5] = f2b(hi.y); t[6] = f2b(hi.z); t[7] = f2b(hi.w);
        a[k0] = t;
    }
    f32x4 acc[8];
#pragma unroll
    for (int c0 = 0; c0 < 8; ++c0) {
        const float bv = bias[c0 * 16 + r];
        acc[c0] = (f32x4){bv, bv, bv, bv};
    }
#pragma unroll
    for (int k0 = 0; k0 < 4; ++k0)
#pragma unroll
        for (int c0 = 0; c0 < 8; ++c0) {
            const bf16x8 b = *(const bf16x8*)(Wt + (size_t)(c0 * 16 + r) * FIN + k0 * 32 + kb * 8);
            acc[c0] = __builtin_amdgcn_mfma_f32_16x16x32_bf16(a[k0], b, acc[c0], 0, 0, 0);
        }
#pragma unroll
    for (int c0 = 0; c0 < 8; ++c0) {
        const int col = c0 * 16 + r;
#pragma unroll
        for (int v = 0; v < 4; ++v) {
            const int orow = row0 + kb * 4 + v;
            float val = acc[c0][v];
            val = val > 0.f ? val : 0.f;
            const ushort_t ub = f2b(val);
            x [(size_t)orow * NHID + col] = ub;
            x0[(size_t)orow * NHID + col] = ub;
        }
    }
}

// ---- edge gather + mean: one wave per edge; lane owns cols 2l,2l+1 (uint = 2 bf16) ----
__global__ __launch_bounds__(256)
void edge_gather_kernel(const ushort_t* __restrict__ x, const int* __restrict__ rp,
                        const int* __restrict__ ci, float* __restrict__ Xe,
                        float* __restrict__ out_xe) {
    const int e = (blockIdx.x * 256 + threadIdx.x) >> 6;
    const int lane = threadIdx.x & 63;
    if (e >= EDGES) return;
    const int beg = rp[e], end = rp[e + 1];
    float a0 = 0.f, a1 = 0.f;
    for (int base = beg; base < end; base += 64) {
        const int m = min(64, end - base);
        const int id = (lane < m) ? ci[base + lane] : 0;
#pragma unroll 4
        for (int j = 0; j < m; ++j) {
            const int row = __shfl(id, j);
            const unsigned u = *(const unsigned*)(x + (size_t)row * NHID + 2 * lane);
            a0 += u2f(u << 16);
            a1 += u2f(u & 0xffff0000u);
        }
    }
    const float inv = 1.f / (float)max(end - beg, 1);
    const float2 v = {a0 * inv, a1 * inv};
    *(float2*)(Xe + (size_t)e * NHID + 2 * lane) = v;
    if (out_xe) *(float2*)(out_xe + (size_t)e * NHID + 2 * lane) = v;
}

// ---- node gather + mean + L2-normalize + residual: one wave per vertex (float2/row) ----
__global__ __launch_bounds__(256)
void node_gather_post_kernel(const float* __restrict__ Xe, const int* __restrict__ rp,
                             const int* __restrict__ ci, const ushort_t* __restrict__ x0,
                             ushort_t* __restrict__ x) {
    const int v = (blockIdx.x * 256 + threadIdx.x) >> 6;
    const int lane = threadIdx.x & 63;
    if (v >= NODES) return;
    const int beg = rp[v], end = rp[v + 1];
    float a0 = 0.f, a1 = 0.f;
    for (int base = beg; base < end; base += 64) {
        const int m = min(64, end - base);
        const int id = (lane < m) ? ci[base + lane] : 0;
#pragma unroll 4
        for (int j = 0; j < m; ++j) {
            const int row = __shfl(id, j);
            const float2 u = *(const float2*)(Xe + (size_t)row * NHID + 2 * lane);
            a0 += u.x;
            a1 += u.y;
        }
    }
    const float inv = 1.f / (float)max(end - beg, 1);
    const float m0 = a0 * inv, m1 = a1 * inv;
    float s = m0 * m0 + m1 * m1;
#pragma unroll
    for (int o = 32; o > 0; o >>= 1) s += __shfl_xor(s, o);
    const float norm = sqrtf(s);
    const float scale = norm > 0.f ? 1.f / fmaxf(norm, 1e-30f) : 0.f;
    const size_t off = (size_t)v * NHID + 2 * lane;
    const unsigned ux0 = *(const unsigned*)(x0 + off);
    const float x00 = u2f(ux0 << 16);
    const float x01 = u2f(ux0 & 0xffff0000u);
    const unsigned lo = f2b(0.9f * m0 * scale + 0.1f * x00);
    const unsigned hi = f2b(0.9f * m1 * scale + 0.1f * x01);
    *(unsigned*)(x + off) = lo | (hi << 16);
}

// ---- layer GEMM (MFMA, in place): x = relu((1-beta)*x + beta*(x @ W)) ----
__global__ __launch_bounds__(256)
void layer_gemm_kernel(ushort_t* __restrict__ x, const ushort_t* __restrict__ Wt, float beta) {
    const int lane = threadIdx.x & 63, wave = threadIdx.x >> 6;
    const int row0 = blockIdx.x * 64 + wave * 16;
    if (row0 >= NODES) return;
    const int r = lane & 15, kb = lane >> 4;
    const int row = row0 + r;
    bf16x8 a[4];
#pragma unroll
    for (int k0 = 0; k0 < 4; ++k0)
        a[k0] = *(const bf16x8*)(x + (size_t)row * NHID + k0 * 32 + kb * 8);
    f32x4 acc[8] = {};
#pragma unroll
    for (int k0 = 0; k0 < 4; ++k0)
#pragma unroll
        for (int c0 = 0; c0 < 8; ++c0) {
            const bf16x8 b = *(const bf16x8*)(Wt + (size_t)(c0 * 16 + r) * NHID + k0 * 32 + kb * 8);
            acc[c0] = __builtin_amdgcn_mfma_f32_16x16x32_bf16(a[k0], b, acc[c0], 0, 0, 0);
        }
#pragma unroll
    for (int c0 = 0; c0 < 8; ++c0) {
        const int col = c0 * 16 + r;
#pragma unroll
        for (int v = 0; v < 4; ++v) {
            const int orow = row0 + kb * 4 + v;
            const size_t off = (size_t)orow * NHID + col;
            const float xi = b2f(x[off]);
            float val = (1.f - beta) * xi + beta * acc[c0][v];
            val = val > 0.f ? val : 0.f;
            x[off] = f2b(val);
        }
    }
}

// ---- output GEMM (MFMA): out = x @ Wout + bout (f32 out) ----
__global__ __launch_bounds__(256)
void out_gemm_kernel(const ushort_t* __restrict__ x, const ushort_t* __restrict__ Wt,
                     const float* __restrict__ bias, float* __restrict__ out) {
    const int lane = threadIdx.x & 63, wave = threadIdx.x >> 6;
    const int row0 = blockIdx.x * 64 + wave * 16;
    if (row0 >= NODES) return;
    const int r = lane & 15, kb = lane >> 4;
    const int row = row0 + r;
    bf16x8 a[4];
#pragma unroll
    for (int k0 = 0; k0 < 4; ++k0)
        a[k0] = *(const bf16x8*)(x + (size_t)row * NHID + k0 * 32 + kb * 8);
    f32x4 acc[4];
#pragma unroll
    for (int c0 = 0; c0 < 4; ++c0) {
        const float bv = bias[c0 * 16 + r];
        acc[c0] = (f32x4){bv, bv, bv, bv};
    }
#pragma unroll
    for (int k0 = 0; k0 < 4; ++k0)
#pragma unroll
        for (int c0 = 0; c0 < 4; ++c0) {
            const bf16x8 b = *(const bf16x8*)(Wt + (size_t)(c0 * 16 + r) * NHID + k0 * 32 + kb * 8);
            acc[c0] = __builtin_amdgcn_mfma_f32_16x16x32_bf16(a[k0], b, acc[c0], 0, 0, 0);
        }
#pragma unroll
    for (int c0 = 0; c0 < 4; ++c0) {
        const int col = c0 * 16 + r;
#pragma unroll
        for (int v = 0; v < 4; ++v) {
            const int orow = row0 + kb * 4 + v;
            out[(size_t)orow * FOUT + col] = acc[c0][v];
        }
    }
}

extern "C" void kernel_launch(void* const* d_in, const int* in_sizes, int n_in,
                              void* d_out, int out_size, void* d_ws, size_t ws_size,
                              hipStream_t stream) {
    const float* x_in  = (const float*)d_in[0];
    const float* W0    = (const float*)d_in[1];
    const float* b0    = (const float*)d_in[2];
    const float* Ws    = (const float*)d_in[3];
    const float* Wout  = (const float*)d_in[4];
    const float* bout  = (const float*)d_in[5];
    const int* vertex  = (const int*)d_in[6];
    const int* edges   = (const int*)d_in[7];

    float* Xe      = (float*)d_ws;                          // EDGES*NHID f32
    ushort_t* x    = (ushort_t*)(Xe + (size_t)EDGES * NHID);// NODES*NHID bf16
    ushort_t* x0   = x  + (size_t)NODES * NHID;             // NODES*NHID bf16
    ushort_t* Wt0  = x0 + (size_t)NODES * NHID;             // 128*128
    ushort_t* WsT  = Wt0 + 128 * 128;                       // 2*128*128
    ushort_t* WoutT= WsT + 2 * 128 * 128;                   // 64*128
    int* cnt_e = (int*)(WoutT + 64 * 128);                  // EDGES
    int* cnt_v = cnt_e + EDGES;                             // NODES
    int* rp_e  = cnt_v + NODES;                             // EDGES+1
    int* rp_v  = rp_e + EDGES + 1;                          // NODES+1
    int* rank_e= rp_v + NODES + 1;                          // NNZ
    int* rank_v= rank_e + NNZ;                              // NNZ
    int* col_e = rank_v + NNZ;                              // NNZ
    int* col_v = col_e + NNZ;                               // NNZ

    float* out    = (float*)d_out;                          // [NODES, FOUT]
    float* out_xe = out + (size_t)NODES * FOUT;             // [EDGES, NHID]

    // ---- CSR build + weight conversion ----
    hipMemsetAsync(cnt_e, 0, (size_t)(EDGES + NODES) * sizeof(int), stream);
    wconv_kernel<<<128, 256, 0, stream>>>(W0, Ws, Wout, Wt0, WsT, WoutT);
    hist_kernel<<<(NNZ + 255) / 256, 256, 0, stream>>>(vertex, edges, cnt_v, cnt_e,
                                                       rank_v, rank_e);
    scan_kernel<<<2, 1024, 0, stream>>>(cnt_e, rp_e, cnt_v, rp_v);
    fill_kernel<<<(NNZ + 255) / 256, 256, 0, stream>>>(vertex, edges, rank_e, rank_v,
                                                       rp_e, rp_v, col_e, col_v);

    const int gemm_grid = (NODES + 63) / 64;
    gemm_in_kernel<<<gemm_grid, 256, 0, stream>>>(x_in, Wt0, b0, x, x0);

    const float betas[2] = {logf(1.5f), logf(1.25f)};  // log(0.5/(i+1)+1)
    for (int i = 0; i < 2; ++i) {
        edge_gather_kernel<<<(EDGES * 64) / 256, 256, 0, stream>>>(
            x, rp_e, col_e, Xe, (i == 1) ? out_xe : (float*)nullptr);
        node_gather_post_kernel<<<(NODES * 64) / 256, 256, 0, stream>>>(
            Xe, rp_v, col_v, x0, x);
        layer_gemm_kernel<<<gemm_grid, 256, 0, stream>>>(x, WsT + (size_t)i * NHID * NHID,
                                                         betas[i]);
    }

    out_gemm_kernel<<<gemm_grid, 256, 0, stream>>>(x, WoutT, bout, out);
}

// Round 6
// 477.463 us; speedup vs baseline: 11.8432x; 1.0451x over previous
//
#include <hip/hip_runtime.h>
#include <hip/hip_bf16.h>
#include <math.h>

#define NODES 50000
#define EDGES 10000
#define NNZ   800000
#define FIN   128
#define NHID  128
#define FOUT  64

#define HIST_BLOCKS  (NNZ / 256)          // 3125
#define WCONV_BLOCKS 128
#define FILL_BLOCKS  (NNZ / 256)          // 3125
#define GEMM_BLOCKS  ((NODES + 63) / 64)  // 782

typedef __attribute__((ext_vector_type(8))) short bf16x8;
typedef __attribute__((ext_vector_type(4))) float f32x4;
typedef unsigned short ushort_t;

__device__ __forceinline__ ushort_t f2b(float f) {
    __hip_bfloat16 h = __float2bfloat16(f);
    return *reinterpret_cast<ushort_t*>(&h);
}
__device__ __forceinline__ float b2f(ushort_t u) {
    __hip_bfloat16 h;
    *reinterpret_cast<ushort_t*>(&h) = u;
    return __bfloat162float(h);
}
__device__ __forceinline__ float u2f(unsigned u) {
    union { unsigned u; float f; } c; c.u = u; return c.f;
}

// ---- fused: histogram+rank (blocks 0..HIST-1) | weight transpose/convert (rest) ----
__global__ __launch_bounds__(256)
void hist_wconv_kernel(const int* __restrict__ vertex, const int* __restrict__ edges,
                       int* __restrict__ cnt_v, int* __restrict__ cnt_e,
                       int* __restrict__ rank_v, int* __restrict__ rank_e,
                       const float* __restrict__ W0, const float* __restrict__ Ws,
                       const float* __restrict__ Wout,
                       ushort_t* __restrict__ Wt0, ushort_t* __restrict__ WsT,
                       ushort_t* __restrict__ WoutT) {
    if (blockIdx.x < HIST_BLOCKS) {
        const int i = blockIdx.x * 256 + threadIdx.x;
        const int re = atomicAdd(&cnt_e[edges[i]], 1);
        __builtin_nontemporal_store(re, &rank_e[i]);
        const int rv = atomicAdd(&cnt_v[vertex[i]], 1);
        __builtin_nontemporal_store(rv, &rank_v[i]);
    } else {
        const int i = (blockIdx.x - HIST_BLOCKS) * 256 + threadIdx.x;
        if (i < 128 * 128) { int c = i >> 7, k = i & 127; Wt0[c * 128 + k] = f2b(W0[k * 128 + c]); }
        if (i < 2 * 128 * 128) {
            int l = i >> 14, r = i & 16383, c = r >> 7, k = r & 127;
            WsT[l * 16384 + c * 128 + k] = f2b(Ws[l * 16384 + k * 128 + c]);
        }
        if (i < 64 * 128) { int c = i >> 7, k = i & 127; WoutT[c * 128 + k] = f2b(Wout[k * 64 + c]); }
    }
}

// ---- exclusive scan (one block per array) ----
__global__ __launch_bounds__(1024)
void scan_kernel(const int* __restrict__ cnt_e, int* __restrict__ rp_e,
                 const int* __restrict__ cnt_v, int* __restrict__ rp_v) {
    const int* cnt = (blockIdx.x == 0) ? cnt_e : cnt_v;
    int* rp  = (blockIdx.x == 0) ? rp_e  : rp_v;
    const int n = (blockIdx.x == 0) ? EDGES : NODES;

    __shared__ int wsum[16];
    __shared__ int carry_sh;
    const int t = threadIdx.x, lane = t & 63, w = t >> 6;
    if (t == 0) carry_sh = 0;
    __syncthreads();
    for (int base = 0; base < n; base += 1024) {
        const int v = (base + t < n) ? cnt[base + t] : 0;
        int x = v;
#pragma unroll
        for (int o = 1; o < 64; o <<= 1) {
            int y = __shfl_up(x, o);
            if (lane >= o) x += y;
        }
        if (lane == 63) wsum[w] = x;
        __syncthreads();
        if (t < 16) {
            int s = wsum[t];
#pragma unroll
            for (int o = 1; o < 16; o <<= 1) {
                int y = __shfl_up(s, o);
                if (t >= o) s += y;
            }
            wsum[t] = s;
        }
        __syncthreads();
        const int incl = x + (w ? wsum[w - 1] : 0);
        const int carry = carry_sh;
        if (base + t < n) rp[base + t] = carry + incl - v;
        __syncthreads();
        if (t == 1023) carry_sh = carry + wsum[15];
        __syncthreads();
    }
    if (t == 0) rp[n] = carry_sh;
}

// ---- fused: CSR fill (blocks 0..FILL-1) | input GEMM (rest) ----
// fill: position = rp[key] + rank (independent scattered stores, no RMW chain)
// gemm: x = x0 = relu(Xin @ W0 + b0), bf16 out (MFMA 16x16x32)
__global__ __launch_bounds__(256)
void fill_gemm_kernel(const int* __restrict__ vertex, const int* __restrict__ edges,
                      const int* __restrict__ rank_e, const int* __restrict__ rank_v,
                      const int* __restrict__ rp_e, const int* __restrict__ rp_v,
                      int* __restrict__ col_e, int* __restrict__ col_v,
                      const float* __restrict__ X, const ushort_t* __restrict__ Wt,
                      const float* __restrict__ bias,
                      ushort_t* __restrict__ x, ushort_t* __restrict__ x0) {
    if (blockIdx.x < FILL_BLOCKS) {
        const int i = blockIdx.x * 256 + threadIdx.x;
        const int e = edges[i], v = vertex[i];
        __builtin_nontemporal_store(v, &col_e[rp_e[e] + rank_e[i]]);
        __builtin_nontemporal_store(e, &col_v[rp_v[v] + rank_v[i]]);
        return;
    }
    const int lane = threadIdx.x & 63, wave = threadIdx.x >> 6;
    const int row0 = (blockIdx.x - FILL_BLOCKS) * 64 + wave * 16;
    if (row0 >= NODES) return;
    const int r = lane & 15, kb = lane >> 4;
    const int row = row0 + r;
    bf16x8 a[4];
#pragma unroll
    for (int k0 = 0; k0 < 4; ++k0) {
        const float* p = X + (size_t)row * FIN + k0 * 32 + kb * 8;
        const float4 lo = *(const float4*)p;
        const float4 hi = *(const float4*)(p + 4);
        bf16x8 t;
        t[0] = f2b(lo.x); t[1] = f2b(lo.y); t[2] = f2b(lo.z); t[3] = f2b(lo.w);
        t[4] = f2b(hi.x); t[5] = f2b(hi.y); t[6] = f2b(hi.z); t[7] = f2b(hi.w);
        a[k0] = t;
    }
    f32x4 acc[8];
#pragma unroll
    for (int c0 = 0; c0 < 8; ++c0) {
        const float bv = bias[c0 * 16 + r];
        acc[c0] = (f32x4){bv, bv, bv, bv};
    }
#pragma unroll
    for (int k0 = 0; k0 < 4; ++k0)
#pragma unroll
        for (int c0 = 0; c0 < 8; ++c0) {
            const bf16x8 b = *(const bf16x8*)(Wt + (size_t)(c0 * 16 + r) * FIN + k0 * 32 + kb * 8);
            acc[c0] = __builtin_amdgcn_mfma_f32_16x16x32_bf16(a[k0], b, acc[c0], 0, 0, 0);
        }
#pragma unroll
    for (int c0 = 0; c0 < 8; ++c0) {
        const int col = c0 * 16 + r;
#pragma unroll
        for (int v = 0; v < 4; ++v) {
            const int orow = row0 + kb * 4 + v;
            float val = acc[c0][v];
            val = val > 0.f ? val : 0.f;
            const ushort_t ub = f2b(val);
            x [(size_t)orow * NHID + col] = ub;
            x0[(size_t)orow * NHID + col] = ub;
        }
    }
}

// ---- edge gather + mean: one wave per edge; Xe stored bf16; f32 copy to output ----
__global__ __launch_bounds__(256)
void edge_gather_kernel(const ushort_t* __restrict__ x, const int* __restrict__ rp,
                        const int* __restrict__ ci, ushort_t* __restrict__ Xe,
                        float* __restrict__ out_xe) {
    const int e = (blockIdx.x * 256 + threadIdx.x) >> 6;
    const int lane = threadIdx.x & 63;
    if (e >= EDGES) return;
    const int beg = rp[e], end = rp[e + 1];
    float a0 = 0.f, a1 = 0.f;
    for (int base = beg; base < end; base += 64) {
        const int m = min(64, end - base);
        const int id = (lane < m) ? ci[base + lane] : 0;
#pragma unroll 4
        for (int j = 0; j < m; ++j) {
            const int row = __shfl(id, j);
            const unsigned u = *(const unsigned*)(x + (size_t)row * NHID + 2 * lane);
            a0 += u2f(u << 16);
            a1 += u2f(u & 0xffff0000u);
        }
    }
    const float inv = 1.f / (float)max(end - beg, 1);
    const float v0 = a0 * inv, v1 = a1 * inv;
    const unsigned lo = f2b(v0), hi = f2b(v1);
    *(unsigned*)(Xe + (size_t)e * NHID + 2 * lane) = lo | (hi << 16);
    if (out_xe) {
        const float2 v = {v0, v1};
        *(float2*)(out_xe + (size_t)e * NHID + 2 * lane) = v;
    }
}

// ---- node gather + mean + L2-normalize + residual: one wave per vertex (bf16 Xe) ----
__global__ __launch_bounds__(256)
void node_gather_post_kernel(const ushort_t* __restrict__ Xe, const int* __restrict__ rp,
                             const int* __restrict__ ci, const ushort_t* __restrict__ x0,
                             ushort_t* __restrict__ x) {
    const int v = (blockIdx.x * 256 + threadIdx.x) >> 6;
    const int lane = threadIdx.x & 63;
    if (v >= NODES) return;
    const int beg = rp[v], end = rp[v + 1];
    float a0 = 0.f, a1 = 0.f;
    for (int base = beg; base < end; base += 64) {
        const int m = min(64, end - base);
        const int id = (lane < m) ? ci[base + lane] : 0;
#pragma unroll 4
        for (int j = 0; j < m; ++j) {
            const int row = __shfl(id, j);
            const unsigned u = *(const unsigned*)(Xe + (size_t)row * NHID + 2 * lane);
            a0 += u2f(u << 16);
            a1 += u2f(u & 0xffff0000u);
        }
    }
    const float inv = 1.f / (float)max(end - beg, 1);
    const float m0 = a0 * inv, m1 = a1 * inv;
    float s = m0 * m0 + m1 * m1;
#pragma unroll
    for (int o = 32; o > 0; o >>= 1) s += __shfl_xor(s, o);
    const float norm = sqrtf(s);
    const float scale = norm > 0.f ? 1.f / fmaxf(norm, 1e-30f) : 0.f;
    const size_t off = (size_t)v * NHID + 2 * lane;
    const unsigned ux0 = *(const unsigned*)(x0 + off);
    const float x00 = u2f(ux0 << 16);
    const float x01 = u2f(ux0 & 0xffff0000u);
    const unsigned lo = f2b(0.9f * m0 * scale + 0.1f * x00);
    const unsigned hi = f2b(0.9f * m1 * scale + 0.1f * x01);
    *(unsigned*)(x + off) = lo | (hi << 16);
}

// ---- layer GEMM (MFMA, in place): x = relu((1-beta)*x + beta*(x @ W)) ----
__global__ __launch_bounds__(256)
void layer_gemm_kernel(ushort_t* __restrict__ x, const ushort_t* __restrict__ Wt, float beta) {
    const int lane = threadIdx.x & 63, wave = threadIdx.x >> 6;
    const int row0 = blockIdx.x * 64 + wave * 16;
    if (row0 >= NODES) return;
    const int r = lane & 15, kb = lane >> 4;
    const int row = row0 + r;
    bf16x8 a[4];
#pragma unroll
    for (int k0 = 0; k0 < 4; ++k0)
        a[k0] = *(const bf16x8*)(x + (size_t)row * NHID + k0 * 32 + kb * 8);
    f32x4 acc[8] = {};
#pragma unroll
    for (int k0 = 0; k0 < 4; ++k0)
#pragma unroll
        for (int c0 = 0; c0 < 8; ++c0) {
            const bf16x8 b = *(const bf16x8*)(Wt + (size_t)(c0 * 16 + r) * NHID + k0 * 32 + kb * 8);
            acc[c0] = __builtin_amdgcn_mfma_f32_16x16x32_bf16(a[k0], b, acc[c0], 0, 0, 0);
        }
#pragma unroll
    for (int c0 = 0; c0 < 8; ++c0) {
        const int col = c0 * 16 + r;
#pragma unroll
        for (int v = 0; v < 4; ++v) {
            const int orow = row0 + kb * 4 + v;
            const size_t off = (size_t)orow * NHID + col;
            const float xi = b2f(x[off]);
            float val = (1.f - beta) * xi + beta * acc[c0][v];
            val = val > 0.f ? val : 0.f;
            x[off] = f2b(val);
        }
    }
}

// ---- output GEMM (MFMA): out = x @ Wout + bout (f32 out) ----
__global__ __launch_bounds__(256)
void out_gemm_kernel(const ushort_t* __restrict__ x, const ushort_t* __restrict__ Wt,
                     const float* __restrict__ bias, float* __restrict__ out) {
    const int lane = threadIdx.x & 63, wave = threadIdx.x >> 6;
    const int row0 = blockIdx.x * 64 + wave * 16;
    if (row0 >= NODES) return;
    const int r = lane & 15, kb = lane >> 4;
    const int row = row0 + r;
    bf16x8 a[4];
#pragma unroll
    for (int k0 = 0; k0 < 4; ++k0)
        a[k0] = *(const bf16x8*)(x + (size_t)row * NHID + k0 * 32 + kb * 8);
    f32x4 acc[4];
#pragma unroll
    for (int c0 = 0; c0 < 4; ++c0) {
        const float bv = bias[c0 * 16 + r];
        acc[c0] = (f32x4){bv, bv, bv, bv};
    }
#pragma unroll
    for (int k0 = 0; k0 < 4; ++k0)
#pragma unroll
        for (int c0 = 0; c0 < 4; ++c0) {
            const bf16x8 b = *(const bf16x8*)(Wt + (size_t)(c0 * 16 + r) * NHID + k0 * 32 + kb * 8);
            acc[c0] = __builtin_amdgcn_mfma_f32_16x16x32_bf16(a[k0], b, acc[c0], 0, 0, 0);
        }
#pragma unroll
    for (int c0 = 0; c0 < 4; ++c0) {
        const int col = c0 * 16 + r;
#pragma unroll
        for (int v = 0; v < 4; ++v) {
            const int orow = row0 + kb * 4 + v;
            out[(size_t)orow * FOUT + col] = acc[c0][v];
        }
    }
}

extern "C" void kernel_launch(void* const* d_in, const int* in_sizes, int n_in,
                              void* d_out, int out_size, void* d_ws, size_t ws_size,
                              hipStream_t stream) {
    const float* x_in  = (const float*)d_in[0];
    const float* W0    = (const float*)d_in[1];
    const float* b0    = (const float*)d_in[2];
    const float* Ws    = (const float*)d_in[3];
    const float* Wout  = (const float*)d_in[4];
    const float* bout  = (const float*)d_in[5];
    const int* vertex  = (const int*)d_in[6];
    const int* edges   = (const int*)d_in[7];

    ushort_t* Xe   = (ushort_t*)d_ws;                       // EDGES*NHID bf16 (2.56 MB, L2-resident)
    ushort_t* x    = Xe + (size_t)EDGES * NHID;             // NODES*NHID bf16
    ushort_t* x0   = x  + (size_t)NODES * NHID;             // NODES*NHID bf16
    ushort_t* Wt0  = x0 + (size_t)NODES * NHID;             // 128*128
    ushort_t* WsT  = Wt0 + 128 * 128;                       // 2*128*128
    ushort_t* WoutT= WsT + 2 * 128 * 128;                   // 64*128
    int* cnt_e = (int*)(WoutT + 64 * 128);                  // EDGES
    int* cnt_v = cnt_e + EDGES;                             // NODES
    int* rp_e  = cnt_v + NODES;                             // EDGES+1
    int* rp_v  = rp_e + EDGES + 1;                          // NODES+1
    int* rank_e= rp_v + NODES + 1;                          // NNZ
    int* rank_v= rank_e + NNZ;                              // NNZ
    int* col_e = rank_v + NNZ;                              // NNZ
    int* col_v = col_e + NNZ;                               // NNZ

    float* out    = (float*)d_out;                          // [NODES, FOUT]
    float* out_xe = out + (size_t)NODES * FOUT;             // [EDGES, NHID]

    // ---- CSR build (+weight conversion fused) ----
    hipMemsetAsync(cnt_e, 0, (size_t)(EDGES + NODES) * sizeof(int), stream);
    hist_wconv_kernel<<<HIST_BLOCKS + WCONV_BLOCKS, 256, 0, stream>>>(
        vertex, edges, cnt_v, cnt_e, rank_v, rank_e, W0, Ws, Wout, Wt0, WsT, WoutT);
    scan_kernel<<<2, 1024, 0, stream>>>(cnt_e, rp_e, cnt_v, rp_v);
    fill_gemm_kernel<<<FILL_BLOCKS + GEMM_BLOCKS, 256, 0, stream>>>(
        vertex, edges, rank_e, rank_v, rp_e, rp_v, col_e, col_v,
        x_in, Wt0, b0, x, x0);

    const float betas[2] = {logf(1.5f), logf(1.25f)};  // log(0.5/(i+1)+1)
    for (int i = 0; i < 2; ++i) {
        edge_gather_kernel<<<(EDGES * 64) / 256, 256, 0, stream>>>(
            x, rp_e, col_e, Xe, (i == 1) ? out_xe : (float*)nullptr);
        node_gather_post_kernel<<<(NODES * 64) / 256, 256, 0, stream>>>(
            Xe, rp_v, col_v, x0, x);
        layer_gemm_kernel<<<GEMM_BLOCKS, 256, 0, stream>>>(x, WsT + (size_t)i * NHID * NHID,
                                                           betas[i]);
    }

    out_gemm_kernel<<<GEMM_BLOCKS, 256, 0, stream>>>(x, WoutT, bout, out);
}

// Round 7
// 422.346 us; speedup vs baseline: 13.3887x; 1.1305x over previous
//
#include <hip/hip_runtime.h>
#include <hip/hip_bf16.h>
#include <math.h>

#define NODES 50000
#define EDGES 10000
#define NNZ   800000
#define FIN   128
#define NHID  128
#define FOUT  64

#define HIST_BLOCKS  (NNZ / 256)          // 3125
#define WCONV_BLOCKS 128
#define FILL_BLOCKS  (NNZ / 256)          // 3125
#define GEMM_BLOCKS  ((NODES + 63) / 64)  // 782
#define EDGE_BLOCKS  (EDGES * 64 / 256)   // 2500
#define NODE_BLOCKS  (NODES * 64 / 256)   // 12500

typedef __attribute__((ext_vector_type(8))) short bf16x8;
typedef __attribute__((ext_vector_type(4))) float f32x4;
typedef unsigned short ushort_t;

__device__ __forceinline__ ushort_t f2b(float f) {
    __hip_bfloat16 h = __float2bfloat16(f);
    return *reinterpret_cast<ushort_t*>(&h);
}
__device__ __forceinline__ float u2f(unsigned u) {
    union { unsigned u; float f; } c; c.u = u; return c.f;
}

// ---- K1: histogram+rank of EDGE keys | weight transpose/convert ----
__global__ __launch_bounds__(256)
void hist_e_wconv_kernel(const int* __restrict__ edges,
                         int* __restrict__ cnt_e, int* __restrict__ rank_e,
                         const float* __restrict__ W0, const float* __restrict__ Ws,
                         const float* __restrict__ Wout,
                         ushort_t* __restrict__ Wt0, ushort_t* __restrict__ WsT,
                         ushort_t* __restrict__ WoutT) {
    if (blockIdx.x < HIST_BLOCKS) {
        const int i = blockIdx.x * 256 + threadIdx.x;
        rank_e[i] = atomicAdd(&cnt_e[edges[i]], 1);
    } else {
        const int i = (blockIdx.x - HIST_BLOCKS) * 256 + threadIdx.x;
        if (i < 128 * 128) { int c = i >> 7, k = i & 127; Wt0[c * 128 + k] = f2b(W0[k * 128 + c]); }
        if (i < 2 * 128 * 128) {
            int l = i >> 14, r = i & 16383, c = r >> 7, k = r & 127;
            WsT[l * 16384 + c * 128 + k] = f2b(Ws[l * 16384 + k * 128 + c]);
        }
        if (i < 64 * 128) { int c = i >> 7, k = i & 127; WoutT[c * 128 + k] = f2b(Wout[k * 64 + c]); }
    }
}

// ---- exclusive scan, 8 items/thread, single 1024-thread block ----
__device__ __forceinline__ void scan_impl(const int* __restrict__ cnt, int* __restrict__ rp,
                                          const int n) {
    __shared__ int wsum[16];
    __shared__ int carry_sh;
    const int t = threadIdx.x, lane = t & 63, w = t >> 6;
    if (t == 0) carry_sh = 0;
    __syncthreads();
    for (int base = 0; base < n; base += 8192) {
        const int idx = base + t * 8;
        int v[8];
        if (idx + 8 <= n) {
            const int4 a = *(const int4*)(cnt + idx);
            const int4 b = *(const int4*)(cnt + idx + 4);
            v[0] = a.x; v[1] = a.y; v[2] = a.z; v[3] = a.w;
            v[4] = b.x; v[5] = b.y; v[6] = b.z; v[7] = b.w;
        } else {
#pragma unroll
            for (int j = 0; j < 8; ++j) v[j] = (idx + j < n) ? cnt[idx + j] : 0;
        }
        int sum8 = 0;
#pragma unroll
        for (int j = 0; j < 8; ++j) sum8 += v[j];
        int x = sum8;
#pragma unroll
        for (int o = 1; o < 64; o <<= 1) {
            int y = __shfl_up(x, o);
            if (lane >= o) x += y;
        }
        if (lane == 63) wsum[w] = x;
        __syncthreads();
        if (t < 16) {
            int s = wsum[t];
#pragma unroll
            for (int o = 1; o < 16; o <<= 1) {
                int y = __shfl_up(s, o);
                if (t >= o) s += y;
            }
            wsum[t] = s;
        }
        __syncthreads();
        const int carry = carry_sh;
        int pre = carry + (x - sum8) + (w ? wsum[w - 1] : 0);
        if (idx < n) {
#pragma unroll
            for (int j = 0; j < 8; ++j)
                if (idx + j < n) { rp[idx + j] = pre; pre += v[j]; }
        }
        __syncthreads();
        if (t == 1023) carry_sh = carry + wsum[15];
        __syncthreads();
    }
    if (t == 0) rp[n] = carry_sh;
}

__global__ __launch_bounds__(1024)
void scan_e_kernel(const int* __restrict__ cnt_e, int* __restrict__ rp_e) {
    scan_impl(cnt_e, rp_e, EDGES);
}
__global__ __launch_bounds__(1024)
void scan_v_kernel(const int* __restrict__ cnt_v, int* __restrict__ rp_v) {
    scan_impl(cnt_v, rp_v, NODES);
}

// ---- K3: fill edge-CSR + histogram vertex keys | input GEMM (MFMA) ----
__global__ __launch_bounds__(256)
void fille_histv_gemm_kernel(const int* __restrict__ vertex, const int* __restrict__ edges,
                             const int* __restrict__ rank_e, const int* __restrict__ rp_e,
                             int* __restrict__ col_e,
                             int* __restrict__ cnt_v, int* __restrict__ rank_v,
                             const float* __restrict__ X, const ushort_t* __restrict__ Wt,
                             const float* __restrict__ bias,
                             ushort_t* __restrict__ x, ushort_t* __restrict__ x0) {
    if (blockIdx.x < FILL_BLOCKS) {
        const int i = blockIdx.x * 256 + threadIdx.x;
        const int e = edges[i], v = vertex[i];
        col_e[rp_e[e] + rank_e[i]] = v;
        rank_v[i] = atomicAdd(&cnt_v[v], 1);
        return;
    }
    const int lane = threadIdx.x & 63, wave = threadIdx.x >> 6;
    const int row0 = (blockIdx.x - FILL_BLOCKS) * 64 + wave * 16;
    if (row0 >= NODES) return;
    const int r = lane & 15, kb = lane >> 4;
    const int row = row0 + r;
    bf16x8 a[4];
#pragma unroll
    for (int k0 = 0; k0 < 4; ++k0) {
        const float* p = X + (size_t)row * FIN + k0 * 32 + kb * 8;
        const float4 lo = *(const float4*)p;
        const float4 hi = *(const float4*)(p + 4);
        bf16x8 t;
        t[0] = f2b(lo.x); t[1] = f2b(lo.y); t[2] = f2b(lo.z); t[3] = f2b(lo.w);
        t[4] = f2b(hi.x); t[5] = f2b(hi.y); t[6] = f2b(hi.z); t[7] = f2b(hi.w);
        a[k0] = t;
    }
    f32x4 acc[8];
#pragma unroll
    for (int c0 = 0; c0 < 8; ++c0) {
        const float bv = bias[c0 * 16 + r];
        acc[c0] = (f32x4){bv, bv, bv, bv};
    }
#pragma unroll
    for (int k0 = 0; k0 < 4; ++k0)
#pragma unroll
        for (int c0 = 0; c0 < 8; ++c0) {
            const bf16x8 b = *(const bf16x8*)(Wt + (size_t)(c0 * 16 + r) * FIN + k0 * 32 + kb * 8);
            acc[c0] = __builtin_amdgcn_mfma_f32_16x16x32_bf16(a[k0], b, acc[c0], 0, 0, 0);
        }
#pragma unroll
    for (int c0 = 0; c0 < 8; ++c0) {
        const int col = c0 * 16 + r;
#pragma unroll
        for (int v = 0; v < 4; ++v) {
            const int orow = row0 + kb * 4 + v;
            float val = acc[c0][v];
            val = val > 0.f ? val : 0.f;
            const ushort_t ub = f2b(val);
            x [(size_t)orow * NHID + col] = ub;
            x0[(size_t)orow * NHID + col] = ub;
        }
    }
}

// ---- edge gather body: one wave per edge; Xe bf16; optional f32 copy out ----
__device__ __forceinline__ void edge_gather_body(const int eblk,
                                                 const ushort_t* __restrict__ x,
                                                 const int* __restrict__ rp,
                                                 const int* __restrict__ ci,
                                                 ushort_t* __restrict__ Xe,
                                                 float* __restrict__ out_xe) {
    const int e = (eblk * 256 + (int)threadIdx.x) >> 6;
    const int lane = threadIdx.x & 63;
    if (e >= EDGES) return;
    const int beg = rp[e], end = rp[e + 1];
    float a0 = 0.f, a1 = 0.f;
    for (int base = beg; base < end; base += 64) {
        const int m = min(64, end - base);
        const int id = (lane < m) ? ci[base + lane] : 0;
#pragma unroll 4
        for (int j = 0; j < m; ++j) {
            const int row = __shfl(id, j);
            const unsigned u = *(const unsigned*)(x + (size_t)row * NHID + 2 * lane);
            a0 += u2f(u << 16);
            a1 += u2f(u & 0xffff0000u);
        }
    }
    const float inv = 1.f / (float)max(end - beg, 1);
    const float v0 = a0 * inv, v1 = a1 * inv;
    const unsigned lo = f2b(v0), hi = f2b(v1);
    *(unsigned*)(Xe + (size_t)e * NHID + 2 * lane) = lo | (hi << 16);
    if (out_xe) {
        const float2 v = {v0, v1};
        *(float2*)(out_xe + (size_t)e * NHID + 2 * lane) = v;
    }
}

// ---- K5: fill vertex-CSR | edge gather (layer 1) ----
__global__ __launch_bounds__(256)
void fillv_edgegather_kernel(const int* __restrict__ vertex, const int* __restrict__ edges,
                             const int* __restrict__ rank_v, const int* __restrict__ rp_v,
                             int* __restrict__ col_v,
                             const ushort_t* __restrict__ x, const int* __restrict__ rp_e,
                             const int* __restrict__ col_e, ushort_t* __restrict__ Xe) {
    if (blockIdx.x < FILL_BLOCKS) {
        const int i = blockIdx.x * 256 + threadIdx.x;
        col_v[rp_v[vertex[i]] + rank_v[i]] = edges[i];
        return;
    }
    edge_gather_body(blockIdx.x - FILL_BLOCKS, x, rp_e, col_e, Xe, (float*)nullptr);
}

// ---- edge gather standalone (layer 2, with f32 output copy) ----
__global__ __launch_bounds__(256)
void edge_gather_kernel(const ushort_t* __restrict__ x, const int* __restrict__ rp,
                        const int* __restrict__ ci, ushort_t* __restrict__ Xe,
                        float* __restrict__ out_xe) {
    edge_gather_body(blockIdx.x, x, rp, ci, Xe, out_xe);
}

// ---- node gather + mean + L2-normalize + residual ----
__global__ __launch_bounds__(256)
void node_gather_post_kernel(const ushort_t* __restrict__ Xe, const int* __restrict__ rp,
                             const int* __restrict__ ci, const ushort_t* __restrict__ x0,
                             ushort_t* __restrict__ x) {
    const int v = (blockIdx.x * 256 + threadIdx.x) >> 6;
    const int lane = threadIdx.x & 63;
    if (v >= NODES) return;
    const int beg = rp[v], end = rp[v + 1];
    float a0 = 0.f, a1 = 0.f;
    for (int base = beg; base < end; base += 64) {
        const int m = min(64, end - base);
        const int id = (lane < m) ? ci[base + lane] : 0;
#pragma unroll 4
        for (int j = 0; j < m; ++j) {
            const int row = __shfl(id, j);
            const unsigned u = *(const unsigned*)(Xe + (size_t)row * NHID + 2 * lane);
            a0 += u2f(u << 16);
            a1 += u2f(u & 0xffff0000u);
        }
    }
    const float inv = 1.f / (float)max(end - beg, 1);
    const float m0 = a0 * inv, m1 = a1 * inv;
    float s = m0 * m0 + m1 * m1;
#pragma unroll
    for (int o = 32; o > 0; o >>= 1) s += __shfl_xor(s, o);
    const float norm = sqrtf(s);
    const float scale = norm > 0.f ? 1.f / fmaxf(norm, 1e-30f) : 0.f;
    const size_t off = (size_t)v * NHID + 2 * lane;
    const unsigned ux0 = *(const unsigned*)(x0 + off);
    const float x00 = u2f(ux0 << 16);
    const float x01 = u2f(ux0 & 0xffff0000u);
    const unsigned lo = f2b(0.9f * m0 * scale + 0.1f * x00);
    const unsigned hi = f2b(0.9f * m1 * scale + 0.1f * x01);
    *(unsigned*)(x + off) = lo | (hi << 16);
}

// ---- layer GEMM (MFMA, in place): x = relu((1-beta)*x + beta*(x @ W)) ----
__global__ __launch_bounds__(256)
void layer_gemm_kernel(ushort_t* __restrict__ x, const ushort_t* __restrict__ Wt, float beta) {
    const int lane = threadIdx.x & 63, wave = threadIdx.x >> 6;
    const int row0 = blockIdx.x * 64 + wave * 16;
    if (row0 >= NODES) return;
    const int r = lane & 15, kb = lane >> 4;
    const int row = row0 + r;
    bf16x8 a[4];
#pragma unroll
    for (int k0 = 0; k0 < 4; ++k0)
        a[k0] = *(const bf16x8*)(x + (size_t)row * NHID + k0 * 32 + kb * 8);
    f32x4 acc[8] = {};
#pragma unroll
    for (int k0 = 0; k0 < 4; ++k0)
#pragma unroll
        for (int c0 = 0; c0 < 8; ++c0) {
            const bf16x8 b = *(const bf16x8*)(Wt + (size_t)(c0 * 16 + r) * NHID + k0 * 32 + kb * 8);
            acc[c0] = __builtin_amdgcn_mfma_f32_16x16x32_bf16(a[k0], b, acc[c0], 0, 0, 0);
        }
    const float xi_m = 1.f - beta;
#pragma unroll
    for (int c0 = 0; c0 < 8; ++c0) {
        const int col = c0 * 16 + r;
#pragma unroll
        for (int v = 0; v < 4; ++v) {
            const int orow = row0 + kb * 4 + v;
            const size_t off = (size_t)orow * NHID + col;
            union { ushort_t u; __hip_bfloat16 b; } cv; cv.u = x[off];
            const float xi = __bfloat162float(cv.b);
            float val = xi_m * xi + beta * acc[c0][v];
            val = val > 0.f ? val : 0.f;
            x[off] = f2b(val);
        }
    }
}

// ---- output GEMM (MFMA): out = x @ Wout + bout (f32 out) ----
__global__ __launch_bounds__(256)
void out_gemm_kernel(const ushort_t* __restrict__ x, const ushort_t* __restrict__ Wt,
                     const float* __restrict__ bias, float* __restrict__ out) {
    const int lane = threadIdx.x & 63, wave = threadIdx.x >> 6;
    const int row0 = blockIdx.x * 64 + wave * 16;
    if (row0 >= NODES) return;
    const int r = lane & 15, kb = lane >> 4;
    const int row = row0 + r;
    bf16x8 a[4];
#pragma unroll
    for (int k0 = 0; k0 < 4; ++k0)
        a[k0] = *(const bf16x8*)(x + (size_t)row * NHID + k0 * 32 + kb * 8);
    f32x4 acc[4];
#pragma unroll
    for (int c0 = 0; c0 < 4; ++c0) {
        const float bv = bias[c0 * 16 + r];
        acc[c0] = (f32x4){bv, bv, bv, bv};
    }
#pragma unroll
    for (int k0 = 0; k0 < 4; ++k0)
#pragma unroll
        for (int c0 = 0; c0 < 4; ++c0) {
            const bf16x8 b = *(const bf16x8*)(Wt + (size_t)(c0 * 16 + r) * NHID + k0 * 32 + kb * 8);
            acc[c0] = __builtin_amdgcn_mfma_f32_16x16x32_bf16(a[k0], b, acc[c0], 0, 0, 0);
        }
#pragma unroll
    for (int c0 = 0; c0 < 4; ++c0) {
        const int col = c0 * 16 + r;
#pragma unroll
        for (int v = 0; v < 4; ++v) {
            const int orow = row0 + kb * 4 + v;
            out[(size_t)orow * FOUT + col] = acc[c0][v];
        }
    }
}

extern "C" void kernel_launch(void* const* d_in, const int* in_sizes, int n_in,
                              void* d_out, int out_size, void* d_ws, size_t ws_size,
                              hipStream_t stream) {
    const float* x_in  = (const float*)d_in[0];
    const float* W0    = (const float*)d_in[1];
    const float* b0    = (const float*)d_in[2];
    const float* Ws    = (const float*)d_in[3];
    const float* Wout  = (const float*)d_in[4];
    const float* bout  = (const float*)d_in[5];
    const int* vertex  = (const int*)d_in[6];
    const int* edges   = (const int*)d_in[7];

    ushort_t* Xe   = (ushort_t*)d_ws;                       // EDGES*NHID bf16 (2.56 MB)
    ushort_t* x    = Xe + (size_t)EDGES * NHID;             // NODES*NHID bf16
    ushort_t* x0   = x  + (size_t)NODES * NHID;             // NODES*NHID bf16
    ushort_t* Wt0  = x0 + (size_t)NODES * NHID;             // 128*128
    ushort_t* WsT  = Wt0 + 128 * 128;                       // 2*128*128
    ushort_t* WoutT= WsT + 2 * 128 * 128;                   // 64*128
    int* cnt_e = (int*)(WoutT + 64 * 128);                  // EDGES
    int* cnt_v = cnt_e + EDGES;                             // NODES
    int* rp_e  = cnt_v + NODES;                             // EDGES+1
    int* rp_v  = rp_e + EDGES + 1;                          // NODES+1  (int4 loads need 16B align: offsets all mult of 4 ints ok)
    int* rank_e= rp_v + NODES + 3;                          // NNZ (pad to keep 16B alignment)
    int* rank_v= rank_e + NNZ;                              // NNZ
    int* col_e = rank_v + NNZ;                              // NNZ
    int* col_v = col_e + NNZ;                               // NNZ

    float* out    = (float*)d_out;                          // [NODES, FOUT]
    float* out_xe = out + (size_t)NODES * FOUT;             // [EDGES, NHID]

    hipMemsetAsync(cnt_e, 0, (size_t)(EDGES + NODES) * sizeof(int), stream);

    // K1: edge histogram + weight conversion
    hist_e_wconv_kernel<<<HIST_BLOCKS + WCONV_BLOCKS, 256, 0, stream>>>(
        edges, cnt_e, rank_e, W0, Ws, Wout, Wt0, WsT, WoutT);
    // K2: scan edge counts
    scan_e_kernel<<<1, 1024, 0, stream>>>(cnt_e, rp_e);
    // K3: fill edge-CSR + vertex histogram + input GEMM
    fille_histv_gemm_kernel<<<FILL_BLOCKS + GEMM_BLOCKS, 256, 0, stream>>>(
        vertex, edges, rank_e, rp_e, col_e, cnt_v, rank_v, x_in, Wt0, b0, x, x0);
    // K4: scan vertex counts
    scan_v_kernel<<<1, 1024, 0, stream>>>(cnt_v, rp_v);
    // K5: fill vertex-CSR + layer-1 edge gather
    fillv_edgegather_kernel<<<FILL_BLOCKS + EDGE_BLOCKS, 256, 0, stream>>>(
        vertex, edges, rank_v, rp_v, col_v, x, rp_e, col_e, Xe);

    const float betas[2] = {logf(1.5f), logf(1.25f)};  // log(0.5/(i+1)+1)

    // layer 1 (edge gather already done in K5)
    node_gather_post_kernel<<<NODE_BLOCKS, 256, 0, stream>>>(Xe, rp_v, col_v, x0, x);
    layer_gemm_kernel<<<GEMM_BLOCKS, 256, 0, stream>>>(x, WsT, betas[0]);

    // layer 2
    edge_gather_kernel<<<EDGE_BLOCKS, 256, 0, stream>>>(x, rp_e, col_e, Xe, out_xe);
    node_gather_post_kernel<<<NODE_BLOCKS, 256, 0, stream>>>(Xe, rp_v, col_v, x0, x);
    layer_gemm_kernel<<<GEMM_BLOCKS, 256, 0, stream>>>(x, WsT + (size_t)NHID * NHID, betas[1]);

    out_gemm_kernel<<<GEMM_BLOCKS, 256, 0, stream>>>(x, WoutT, bout, out);
}